// Round 10
// baseline (238.351 us; speedup 1.0000x reference)
//
#include <hip/hip_runtime.h>
#include <stdint.h>

// 7x7 conv, stride 1, pad 3, on 64 x 512 x 512 fp32 (single channel).
// out[n,y,x] = sum_{ky,kx} x[n, y+ky-3, x+kx-3] * w[ky,kx]
//
// R17: REGISTER RING-BUFFER STREAMING. No LDS, no barrier, minimal traffic,
// continuous fine-grained memory issue.
//   - 10-probe ledger: every variant of stage->barrier->LDS-read->FMA sits
//     at ~35-40us regardless of occupancy/ILP/barriers/halo-amortization.
//     The fill kernels hit 6.5 TB/s at 8% occupancy because each wave issues
//     memory CONTINUOUSLY; our variants issue in short bursts then go
//     memory-silent for ~1600 cyc -> time-averaged ~3 TB/s. R13 (streaming,
//     no registers) had continuous issue but 10x logical re-reads -> 189 MB
//     L2-miss traffic. This kernel has both properties at once:
//   - 1 wave per 256x16 strip, sliding in y. Last 7 input rows live in a
//     win[8][12] register ring (static indices after full unroll). Per
//     y-step: 3 f4 loads (row j+7, depth-1 prefetch -> counted vmcnt by
//     compiler), 196 FMAs (output row j), 1 f4 store. Each input row is
//     loaded ONCE per thread; the 3x intra-wave x-overlap (spans shifted
//     +-16B, touched back-to-back) collapses in L1.
//   - 4096 one-wave blocks; ~115 VGPR -> 4 waves/SIMD, 16 independent
//     waves/CU, zero inter-wave coupling.
//   - FMA order per output (ky asc, kx asc, cc) identical to all passing
//     rounds -> identical numerics (absmax 0.125).

#define IMG_W 512
#define IMG_H 512
#define NIMG  64
#define TW    256            // output cols per block (64 lanes x 4)
#define TH    16             // output rows per block
#define NR    (TH + 6)       // 22 input rows touched per strip

__global__ __launch_bounds__(64, 4) void conv7x7_kernel(
    const float* __restrict__ x,
    const float* __restrict__ wgt,
    float* __restrict__ out)
{
    const int lane = threadIdx.x;
    const int bx   = blockIdx.x * TW;
    const int by   = blockIdx.y * TH;
    const int n    = blockIdx.z;

    const float* img = x + (size_t)n * (IMG_W * IMG_H);
    float* o = out + (size_t)n * (IMG_W * IMG_H);

    // ---- weights: wave-uniform -> SGPRs ----
    float w[49];
    #pragma unroll
    for (int i = 0; i < 49; ++i) w[i] = wgt[i];

    const int lx = bx + lane * 4;          // global x of first output col
    const bool has_left  = (lx != 0);
    const bool has_right = (lx != IMG_W - 4);

    // ring of the last 8 input rows, 12 floats each (cols lx-4 .. lx+7)
    float win[8][12];

    // load input row r (gy = by-3+r) into ring slot r&7; zeros when OOB.
    // All win indices are compile-time constants after unrolling.
    #define LOADROW(r)                                                        \
    do {                                                                      \
        const int _gy = by - 3 + (r);                                         \
        float* _s = win[(r) & 7];                                             \
        if ((unsigned)_gy < IMG_H) {           /* wave-uniform branch */      \
            const float* _rp = img + (size_t)_gy * IMG_W + lx;                \
            float4 _a = make_float4(0.f, 0.f, 0.f, 0.f);                      \
            float4 _c = _a;                                                   \
            if (has_left)  _a = *(const float4*)(_rp - 4);                    \
            const float4 _b = *(const float4*)_rp;                            \
            if (has_right) _c = *(const float4*)(_rp + 4);                    \
            _s[0] = _a.x; _s[1] = _a.y; _s[2]  = _a.z; _s[3]  = _a.w;         \
            _s[4] = _b.x; _s[5] = _b.y; _s[6]  = _b.z; _s[7]  = _b.w;         \
            _s[8] = _c.x; _s[9] = _c.y; _s[10] = _c.z; _s[11] = _c.w;         \
        } else {                                                              \
            _Pragma("unroll")                                                 \
            for (int _u = 0; _u < 12; ++_u) _s[_u] = 0.f;                     \
        }                                                                     \
    } while (0)

    // ---- prologue: rows 0..6 ----
    #pragma unroll
    for (int r = 0; r < 7; ++r) LOADROW(r);

    // ---- steady state: prefetch row j+7, compute output j, store ----
    #pragma unroll
    for (int j = 0; j < TH; ++j) {
        if (j + 7 < NR) LOADROW(j + 7);   // consumed at iter j+1 -> latency
                                          // hides under this iter's FMAs
        float acc[4] = {};
        #pragma unroll
        for (int ky = 0; ky < 7; ++ky) {
            const float* row = win[(j + ky) & 7];   // static after unroll
            #pragma unroll
            for (int kx = 0; kx < 7; ++kx) {
                const float wv = w[ky * 7 + kx];
                #pragma unroll
                for (int cc = 0; cc < 4; ++cc)
                    acc[cc] = fmaf(row[1 + kx + cc], wv, acc[cc]);
            }
        }
        *(float4*)&o[(size_t)(by + j) * IMG_W + lx] =
            make_float4(acc[0], acc[1], acc[2], acc[3]);
    }

    #undef LOADROW
}

extern "C" void kernel_launch(void* const* d_in, const int* in_sizes, int n_in,
                              void* d_out, int out_size, void* d_ws, size_t ws_size,
                              hipStream_t stream)
{
    const float* x   = (const float*)d_in[0];
    const float* wgt = (const float*)d_in[1];
    float* out       = (float*)d_out;

    // 2 x 32 x 64 = 4096 blocks of ONE wave each
    dim3 grid(IMG_W / TW, IMG_H / TH, NIMG);
    conv7x7_kernel<<<grid, 64, 0, stream>>>(x, wgt, out);
}